// Round 6
// baseline (523.641 us; speedup 1.0000x reference)
//
#include <hip/hip_runtime.h>
#include <stdint.h>

namespace {

constexpr int Bn = 1024;  // batch
constexpr int Tn = 1024;  // timesteps
constexpr int Hn = 50;    // hidden
constexpr int Pn = 16;    // params per (b,t)
constexpr int KP = 25;    // h pairs (H=50 -> 25 half2)
constexpr int KA = 13;    // chain split: accA gets pairs 0..12, accB 13..24

typedef _Float16 h2 __attribute__((ext_vector_type(2)));

__device__ __forceinline__ float fast_rcp(float x) { return __builtin_amdgcn_rcpf(x); }
__device__ __forceinline__ float fast_sigmoid(float x) {
    return fast_rcp(1.0f + __expf(-x));
}
__device__ __forceinline__ float fast_tanh(float x) {
    return 1.0f - 2.0f * fast_rcp(__expf(2.0f * x) + 1.0f);
}
__device__ __forceinline__ float fdot2(h2 a, h2 b, float c) {
    return __builtin_amdgcn_fdot2(a, b, c, false);  // v_dot2_f32_f16, fp32 acc
}
__device__ __forceinline__ h2 pkfma(h2 a, h2 b, h2 c) {
    return __builtin_elementwise_fma(a, b, c);      // v_pk_fma_f16, full-rate
}

// ---------------------------------------------------------------------------
// Serial kernel: recurrence only. 1 wave per batch element (1024 blocks =
// 1 wave/SIMD chip-wide). Lane j owns hidden unit j (gate rows j, j+50,
// j+100, j+150); W_hh in VGPRs as 100 packed half2, pinned.
// r5 post-mortem: v_dot2_f32_f16 measured ~4cy/wave64 (r3->r5 delta = 4.2cy
// per removed instr). Matvec now uses v_pk_fma_f16 (full-rate packed fp16,
// 2 MACs/2cy) with TWO packed accumulators per gate = 8 independent chains
// (ILP covers ~16cy latency), horizontal-reduced via one fdot2 vs (1,1) per
// accumulator into the fp32 base (x*W_ih + bias). fp16 chain length <= 13.
// Projection deferred to post_proj via packed-h store ([b][k][t] layout).
// ---------------------------------------------------------------------------
__global__ __attribute__((amdgpu_flat_work_group_size(64, 64), amdgpu_waves_per_eu(1, 1)))
void lstm_core_h(const float* __restrict__ x, const float* __restrict__ W_ih,
                 const float* __restrict__ W_hh, const float* __restrict__ b_ih,
                 const float* __restrict__ b_hh, uint32_t* __restrict__ hbuf)
{
    const int b    = blockIdx.x;
    const int lane = threadIdx.x;                 // 0..63
    const int jj   = (lane < Hn) ? lane : Hn - 1; // lanes 50..63: harmless dup

    // --- pack W_hh rows (fp16 RNE) into 100 VGPRs, pinned ---
    h2 w0[KP], w1[KP], w2[KP], w3[KP];
    const float* r0 = W_hh + (size_t)(0 * Hn + jj) * Hn;
    const float* r1 = W_hh + (size_t)(1 * Hn + jj) * Hn;
    const float* r2 = W_hh + (size_t)(2 * Hn + jj) * Hn;
    const float* r3 = W_hh + (size_t)(3 * Hn + jj) * Hn;
    #pragma unroll
    for (int k = 0; k < KP; ++k) {
        w0[k] = h2{(_Float16)r0[2 * k], (_Float16)r0[2 * k + 1]};
        w1[k] = h2{(_Float16)r1[2 * k], (_Float16)r1[2 * k + 1]};
        w2[k] = h2{(_Float16)r2[2 * k], (_Float16)r2[2 * k + 1]};
        w3[k] = h2{(_Float16)r3[2 * k], (_Float16)r3[2 * k + 1]};
    }
    #pragma unroll
    for (int k = 0; k < KP; ++k) {
        asm volatile("" : "+v"(w0[k]), "+v"(w1[k]), "+v"(w2[k]), "+v"(w3[k]));
    }

    const float wih0 = W_ih[0 * Hn + jj];
    const float wih1 = W_ih[1 * Hn + jj];
    const float wih2 = W_ih[2 * Hn + jj];
    const float wih3 = W_ih[3 * Hn + jj];
    const float bb0 = b_ih[0 * Hn + jj] + b_hh[0 * Hn + jj];
    const float bb1 = b_ih[1 * Hn + jj] + b_hh[1 * Hn + jj];
    const float bb2 = b_ih[2 * Hn + jj] + b_hh[2 * Hn + jj];
    const float bb3 = b_ih[3 * Hn + jj] + b_hh[3 * Hn + jj];

    const float4* xb4 = (const float4*)(x + (size_t)b * Tn);

    // packed-h store: even lanes 0,2,..,48 own pair k=lane/2; [b][k][t] layout
    uint32_t* hb = hbuf + ((size_t)b * KP + (size_t)(lane >> 1)) * Tn;
    const bool writer = (lane < Hn) && ((lane & 1) == 0);

    const h2 one2 = h2{(_Float16)1.0f, (_Float16)1.0f};
    const h2 zero2 = h2{(_Float16)0.0f, (_Float16)0.0f};

    float h = 0.0f, c = 0.0f;
    int sp[KP];
    #pragma unroll
    for (int k = 0; k < KP; ++k) sp[k] = 0;

    float4 xA = xb4[0];

    for (int tt = 0; tt < Tn / 4; ++tt) {
        float4 xB = make_float4(0.f, 0.f, 0.f, 0.f);
        if (tt + 1 < Tn / 4) xB = xb4[tt + 1];

        const float xs[4] = {xA.x, xA.y, xA.z, xA.w};

        #pragma unroll
        for (int u = 0; u < 4; ++u) {
            // fp32 bases: x*W_ih + (b_ih + b_hh)
            const float base0 = fmaf(xs[u], wih0, bb0);
            const float base1 = fmaf(xs[u], wih1, bb1);
            const float base2 = fmaf(xs[u], wih2, bb2);
            const float base3 = fmaf(xs[u], wih3, bb3);

            // matvec: 100 v_pk_fma_f16 over 8 independent packed chains
            h2 a0A = zero2, a1A = zero2, a2A = zero2, a3A = zero2;
            h2 a0B = zero2, a1B = zero2, a2B = zero2, a3B = zero2;
            #pragma unroll
            for (int k = 0; k < KA; ++k) {
                const h2 hp = __builtin_bit_cast(h2, sp[k]);
                a0A = pkfma(hp, w0[k], a0A);
                a1A = pkfma(hp, w1[k], a1A);
                a2A = pkfma(hp, w2[k], a2A);
                a3A = pkfma(hp, w3[k], a3A);
            }
            #pragma unroll
            for (int k = KA; k < KP; ++k) {
                const h2 hp = __builtin_bit_cast(h2, sp[k]);
                a0B = pkfma(hp, w0[k], a0B);
                a1B = pkfma(hp, w1[k], a1B);
                a2B = pkfma(hp, w2[k], a2B);
                a3B = pkfma(hp, w3[k], a3B);
            }
            // horizontal reduce (fp32): acc.(1,1) + base
            const float a0 = fdot2(a0A, one2, fdot2(a0B, one2, base0));
            const float a1 = fdot2(a1A, one2, fdot2(a1B, one2, base1));
            const float a2 = fdot2(a2A, one2, fdot2(a2B, one2, base2));
            const float a3 = fdot2(a3A, one2, fdot2(a3B, one2, base3));

            const float ig = fast_sigmoid(a0);
            const float fg = fast_sigmoid(a1);
            const float gg = fast_tanh(a2);
            const float og = fast_sigmoid(a3);
            c = fmaf(fg, c, ig * gg);
            h = og * fast_tanh(c);

            // pack (h_j, h_{j^1}): DPP quad-perm [1,0,3,2] + cvt_pkrtz
            const int hi = __builtin_bit_cast(int, h);
            const int hj = __builtin_amdgcn_update_dpp(0, hi, 0xB1, 0xF, 0xF, true);
            const int packed = __builtin_bit_cast(int,
                __builtin_amdgcn_cvt_pkrtz(h, __builtin_bit_cast(float, hj)));

            // deferred projection: store packed h (fire-and-forget)
            if (writer) hb[tt * 4 + u] = (uint32_t)packed;

            // broadcast for next step's matvec: 25 readlanes -> SGPRs
            #pragma unroll
            for (int k = 0; k < KP; ++k)
                sp[k] = __builtin_amdgcn_readlane(packed, 2 * k);
        }
        xA = xB;
    }
}

// ---------------------------------------------------------------------------
// Post-kernel: out[b,t] = h(b,t).Wlin[0:50] + params(b,t).Wlin[50:66] + b_lin.
// One thread per (b,t); hbuf [b][k][t] -> lane-coalesced dword loads.
// ---------------------------------------------------------------------------
__global__ __launch_bounds__(256)
void post_proj(const uint32_t* __restrict__ hbuf, const float* __restrict__ params,
               const float* __restrict__ W_lin, const float* __restrict__ b_lin,
               float* __restrict__ out)
{
    const int i = blockIdx.x * 256 + threadIdx.x;  // 0 .. B*T-1 (exact grid)
    const int b = i >> 10;                         // Tn = 1024
    const int t = i & (Tn - 1);

    float s = b_lin[0];
    const uint32_t* hp = hbuf + (size_t)b * KP * Tn + t;
    #pragma unroll
    for (int k = 0; k < KP; ++k) {
        const h2 wlk = h2{(_Float16)W_lin[2 * k], (_Float16)W_lin[2 * k + 1]};
        s = fdot2(__builtin_bit_cast(h2, hp[(size_t)k * Tn]), wlk, s);
    }

    const float4* p4 = (const float4*)(params + (size_t)i * Pn);
    const float4 a = p4[0], bq = p4[1], cq = p4[2], dq = p4[3];
    const float* wp = W_lin + Hn;
    s += a.x  * wp[ 0] + a.y  * wp[ 1] + a.z  * wp[ 2] + a.w  * wp[ 3];
    s += bq.x * wp[ 4] + bq.y * wp[ 5] + bq.z * wp[ 6] + bq.w * wp[ 7];
    s += cq.x * wp[ 8] + cq.y * wp[ 9] + cq.z * wp[10] + cq.w * wp[11];
    s += dq.x * wp[12] + dq.y * wp[13] + dq.z * wp[14] + dq.w * wp[15];
    out[i] = s;
}

// ---------------------------------------------------------------------------
// FALLBACK (ws too small for hbuf): round-3 fused kernels, proven correct.
// ---------------------------------------------------------------------------
__global__ __launch_bounds__(256)
void params_proj(const float* __restrict__ params, const float* __restrict__ W_lin,
                 float* __restrict__ pp)
{
    const int i = blockIdx.x * 256 + threadIdx.x;
    const float4* p4 = (const float4*)(params + (size_t)i * Pn);
    const float4 a = p4[0], b = p4[1], c = p4[2], d = p4[3];
    const float* wl = W_lin + Hn;
    float s;
    s  = a.x * wl[ 0] + a.y * wl[ 1] + a.z * wl[ 2] + a.w * wl[ 3];
    s += b.x * wl[ 4] + b.y * wl[ 5] + b.z * wl[ 6] + b.w * wl[ 7];
    s += c.x * wl[ 8] + c.y * wl[ 9] + c.z * wl[10] + c.w * wl[11];
    s += d.x * wl[12] + d.y * wl[13] + d.z * wl[14] + d.w * wl[15];
    pp[i] = s;
}

__global__ __attribute__((amdgpu_flat_work_group_size(64, 64), amdgpu_waves_per_eu(1, 1)))
void lstm_core_fused(const float* __restrict__ x, const float* __restrict__ W_ih,
                     const float* __restrict__ W_hh, const float* __restrict__ b_ih,
                     const float* __restrict__ b_hh, const float* __restrict__ W_lin,
                     const float* __restrict__ b_lin, const float* __restrict__ pp,
                     float* __restrict__ out)
{
    const int b    = blockIdx.x;
    const int lane = threadIdx.x;
    const int jj   = (lane < Hn) ? lane : Hn - 1;

    h2 w0[KP], w1[KP], w2[KP], w3[KP], wl[KP];
    const float* r0 = W_hh + (size_t)(0 * Hn + jj) * Hn;
    const float* r1 = W_hh + (size_t)(1 * Hn + jj) * Hn;
    const float* r2 = W_hh + (size_t)(2 * Hn + jj) * Hn;
    const float* r3 = W_hh + (size_t)(3 * Hn + jj) * Hn;
    #pragma unroll
    for (int k = 0; k < KP; ++k) {
        w0[k] = h2{(_Float16)r0[2 * k], (_Float16)r0[2 * k + 1]};
        w1[k] = h2{(_Float16)r1[2 * k], (_Float16)r1[2 * k + 1]};
        w2[k] = h2{(_Float16)r2[2 * k], (_Float16)r2[2 * k + 1]};
        w3[k] = h2{(_Float16)r3[2 * k], (_Float16)r3[2 * k + 1]};
        wl[k] = h2{(_Float16)W_lin[2 * k], (_Float16)W_lin[2 * k + 1]};
    }
    #pragma unroll
    for (int k = 0; k < KP; ++k) {
        asm volatile("" : "+v"(w0[k]), "+v"(w1[k]), "+v"(w2[k]), "+v"(w3[k]), "+v"(wl[k]));
    }

    const float wih0 = W_ih[0 * Hn + jj];
    const float wih1 = W_ih[1 * Hn + jj];
    const float wih2 = W_ih[2 * Hn + jj];
    const float wih3 = W_ih[3 * Hn + jj];
    const float bb0 = b_ih[0 * Hn + jj] + b_hh[0 * Hn + jj];
    const float bb1 = b_ih[1 * Hn + jj] + b_hh[1 * Hn + jj];
    const float bb2 = b_ih[2 * Hn + jj] + b_hh[2 * Hn + jj];
    const float bb3 = b_ih[3 * Hn + jj] + b_hh[3 * Hn + jj];
    const float blin = b_lin[0];

    const float4* xb4 = (const float4*)(x + (size_t)b * Tn);
    const float4* pp4 = (const float4*)(pp + (size_t)b * Tn);
    float4* ob4 = (float4*)(out + (size_t)b * Tn);

    float h = 0.0f, c = 0.0f;
    int sp[KP];
    #pragma unroll
    for (int k = 0; k < KP; ++k) sp[k] = 0;

    float4 xA = xb4[0], pA = pp4[0];

    for (int tt = 0; tt < Tn / 4; ++tt) {
        float4 xB = make_float4(0.f, 0.f, 0.f, 0.f), pB = xB;
        if (tt + 1 < Tn / 4) { xB = xb4[tt + 1]; pB = pp4[tt + 1]; }

        const float xs[4] = {xA.x, xA.y, xA.z, xA.w};
        const float ps[4] = {pA.x, pA.y, pA.z, pA.w};
        float o4[4];

        #pragma unroll
        for (int u = 0; u < 4; ++u) {
            float a0 = fmaf(xs[u], wih0, bb0);
            float a1 = fmaf(xs[u], wih1, bb1);
            float a2 = fmaf(xs[u], wih2, bb2);
            float a3 = fmaf(xs[u], wih3, bb3);
            #pragma unroll
            for (int k = 0; k < KP; ++k) {
                const h2 hp = __builtin_bit_cast(h2, sp[k]);
                a0 = fdot2(hp, w0[k], a0);
                a1 = fdot2(hp, w1[k], a1);
                a2 = fdot2(hp, w2[k], a2);
                a3 = fdot2(hp, w3[k], a3);
            }

            const float ig = fast_sigmoid(a0);
            const float fg = fast_sigmoid(a1);
            const float gg = fast_tanh(a2);
            const float og = fast_sigmoid(a3);
            c = fmaf(fg, c, ig * gg);
            h = og * fast_tanh(c);

            const int hi = __builtin_bit_cast(int, h);
            const int hj = __builtin_amdgcn_update_dpp(0, hi, 0xB1, 0xF, 0xF, true);
            const int packed = __builtin_bit_cast(int,
                __builtin_amdgcn_cvt_pkrtz(h, __builtin_bit_cast(float, hj)));

            #pragma unroll
            for (int k = 0; k < KP; ++k)
                sp[k] = __builtin_amdgcn_readlane(packed, 2 * k);

            float prj = ps[u] + blin;
            #pragma unroll
            for (int k = 0; k < KP; ++k)
                prj = fdot2(__builtin_bit_cast(h2, sp[k]), wl[k], prj);
            o4[u] = prj;
        }

        if (lane == 0) ob4[tt] = make_float4(o4[0], o4[1], o4[2], o4[3]);
        xA = xB; pA = pB;
    }
}

} // namespace

extern "C" void kernel_launch(void* const* d_in, const int* in_sizes, int n_in,
                              void* d_out, int out_size, void* d_ws, size_t ws_size,
                              hipStream_t stream) {
    const float* x      = (const float*)d_in[0];
    const float* params = (const float*)d_in[1];
    const float* W_ih   = (const float*)d_in[2];
    const float* W_hh   = (const float*)d_in[3];
    const float* b_ih   = (const float*)d_in[4];
    const float* b_hh   = (const float*)d_in[5];
    const float* W_lin  = (const float*)d_in[6];
    const float* b_lin  = (const float*)d_in[7];
    float* out = (float*)d_out;

    const size_t hbuf_bytes = (size_t)Bn * KP * Tn * sizeof(uint32_t);  // 100 MB

    if (ws_size >= hbuf_bytes) {
        uint32_t* hbuf = (uint32_t*)d_ws;
        lstm_core_h<<<dim3(Bn), dim3(64), 0, stream>>>(
            x, W_ih, W_hh, b_ih, b_hh, hbuf);
        post_proj<<<dim3(Bn * Tn / 256), dim3(256), 0, stream>>>(
            hbuf, params, W_lin, b_lin, out);
    } else {
        float* pp = (float*)d_ws;  // 4 MB
        params_proj<<<dim3(Bn * Tn / 256), dim3(256), 0, stream>>>(params, W_lin, pp);
        lstm_core_fused<<<dim3(Bn), dim3(64), 0, stream>>>(
            x, W_ih, W_hh, b_ih, b_hh, W_lin, b_lin, pp, out);
    }
}